// Round 2
// baseline (324.880 us; speedup 1.0000x reference)
//
#include <hip/hip_runtime.h>
#include <hip/hip_bf16.h>
#include <math.h>

typedef __bf16 bf16_t;
typedef __bf16 bf16x8 __attribute__((ext_vector_type(8)));
typedef float f32x4 __attribute__((ext_vector_type(4)));

constexpr int Bc = 2, Tc = 2048, Cdim = 2048, Hc = 16, KVc = 4, HDc = 128;
constexpr int Mc = Bc * Tc;      // 4096
constexpr int Nqkv = 3072;       // fused projection width: 2048 Q + 512 K + 512 V

typedef const __attribute__((address_space(1))) void* as1_cptr;
typedef __attribute__((address_space(3))) void* as3_ptr;

__device__ __forceinline__ void gload_lds16(const bf16_t* g, bf16_t* l) {
  __builtin_amdgcn_global_load_lds((as1_cptr)(const void*)g, (as3_ptr)(void*)l, 16, 0, 0);
}

__device__ __forceinline__ unsigned int cvt_pk_bf16(float lo, float hi) {
  unsigned int r;
  asm("v_cvt_pk_bf16_f32 %0, %1, %2" : "=v"(r) : "v"(lo), "v"(hi));
  return r;
}
__device__ __forceinline__ void perm32swap(unsigned int& a, unsigned int& b) {
  asm("v_permlane32_swap_b32 %0, %1" : "+v"(a), "+v"(b));
}
__device__ __forceinline__ void perm16swap(unsigned int& a, unsigned int& b) {
  asm("v_permlane16_swap_b32 %0, %1" : "+v"(a), "+v"(b));
}

// ---------------- elementwise f32 -> bf16 (x) ----------------
__global__ void k_cvt_bf16(const float* __restrict__ in, bf16_t* __restrict__ out) {
  int i = (blockIdx.x * 256 + threadIdx.x) * 8;
  float4 a = *(const float4*)(in + i);
  float4 b = *(const float4*)(in + i + 4);
  bf16x8 v;
  v[0] = (bf16_t)a.x; v[1] = (bf16_t)a.y; v[2] = (bf16_t)a.z; v[3] = (bf16_t)a.w;
  v[4] = (bf16_t)b.x; v[5] = (bf16_t)b.y; v[6] = (bf16_t)b.z; v[7] = (bf16_t)b.w;
  *(bf16x8*)(out + i) = v;
}

// ---------------- W [K,N] f32 -> Wt [N,K] bf16 ----------------
__global__ void k_w_trans(const float* __restrict__ W, bf16_t* __restrict__ Wt,
                          int K, int N) {
  __shared__ alignas(16) bf16_t tile[64][72];
  const int k0 = blockIdx.x * 64, n0 = blockIdx.y * 64;
  const int t = threadIdx.x;
#pragma unroll
  for (int i = 0; i < 4; ++i) {
    int idx = t + i * 256;
    int r = idx >> 4;
    int c4 = (idx & 15) * 4;
    float4 v = *(const float4*)(W + (size_t)(k0 + r) * N + n0 + c4);
    tile[r][c4 + 0] = (bf16_t)v.x; tile[r][c4 + 1] = (bf16_t)v.y;
    tile[r][c4 + 2] = (bf16_t)v.z; tile[r][c4 + 3] = (bf16_t)v.w;
  }
  __syncthreads();
#pragma unroll
  for (int i = 0; i < 4; ++i) {
    int idx = t + i * 256;
    int n = idx >> 4;
    int kc = (idx & 15) * 4;
    alignas(8) bf16_t o[4];
#pragma unroll
    for (int j = 0; j < 4; ++j) o[j] = tile[kc + j][n];
    *(uint2*)(Wt + (size_t)(n0 + n) * K + k0 + kc) = *(uint2*)o;
  }
}

// ---------------- GEMM 256x256, BK=64, 8-phase counted-vmcnt pipeline ----
// 8 waves (2M x 4N), per-wave output 128x64 (acc[8][4] f32x4).
// LDS 128KB: A/B each [2 buf][2 half][128x64] bf16, XOR-swizzled 8-slot rows
// (linear gload_lds dest + inverse-swizzled global source + swizzled read).
// Staging lead: A-halves of step s+1 at phases 0/1; B-halves of step s+2 at
// phases 2/3 (into regions that died this step). Waits are counted:
// vmcnt(8) end of phase 1, vmcnt(6) end of phase 3; tail peels 2 -> 0.
template <typename OutT>
__global__ __launch_bounds__(512, 2) void k_gemm256(
    const bf16_t* __restrict__ A, const bf16_t* __restrict__ Bt,
    OutT* __restrict__ Cout, int M, int N, int K) {
  __shared__ alignas(16) bf16_t Ash[2][2][128 * 64];
  __shared__ alignas(16) bf16_t Bsh[2][2][128 * 64];
  const int tid = threadIdx.x;
  const int wave = tid >> 6, lane = tid & 63;
  const int col = lane & 15, quad = lane >> 4;
  const int wr = wave >> 2, wc = wave & 3;

  // XCD-bijective swizzle (both grids here are multiples of 8)
  const int nwg = gridDim.x * gridDim.y;
  int wg = blockIdx.y * gridDim.x + blockIdx.x;
  wg = (wg & 7) * (nwg >> 3) + (wg >> 3);
  const int bx = wg % gridDim.x, by = wg / gridDim.x;
  const int m0 = by * 256, n0 = bx * 256;

  // staging geometry: per gload issue a wave covers 8 rows x 64 cols
  const int stg_row = wave * 8 + (lane >> 3);          // row within 64-row region
  const int stg_sl8 = ((lane & 7) ^ (lane >> 3)) * 8;  // pre-swizzled source slot

  auto stageA = [&](int tb, int r, int sidx) {
#pragma unroll
    for (int h = 0; h < 2; ++h)
      gload_lds16(A + (size_t)(m0 + h * 128 + r * 64 + stg_row) * K + sidx * 64 + stg_sl8,
                  &Ash[tb][h][(r * 64 + wave * 8) * 64]);
  };
  auto stageB = [&](int tb, int h, int sidx) {
#pragma unroll
    for (int r = 0; r < 2; ++r)
      gload_lds16(Bt + (size_t)(n0 + h * 128 + r * 64 + stg_row) * K + sidx * 64 + stg_sl8,
                  &Bsh[tb][h][(r * 64 + wave * 8) * 64]);
  };
  auto frag = [&](const bf16_t* H, int r, int kc) {
    return *(const bf16x8*)(H + r * 64 + (((kc * 4 + quad) ^ (r & 7)) * 8));
  };

  f32x4 acc[8][4];
#pragma unroll
  for (int i = 0; i < 8; ++i)
#pragma unroll
    for (int j = 0; j < 4; ++j) acc[i][j] = f32x4{0.f, 0.f, 0.f, 0.f};

  const int NSTEP = K >> 6;

  // prologue: B_0 (4), A_0 R0 (2), A_0 R1 (2), B_1 (4); wait first 6 groups
  stageB(0, 0, 0); stageB(0, 1, 0);
  stageA(0, 0, 0); stageA(0, 1, 0);
  stageB(1, 0, 1); stageB(1, 1, 1);
  asm volatile("s_waitcnt vmcnt(6)" ::: "memory");
  asm volatile("s_barrier" ::: "memory");

#pragma unroll 1
  for (int s = 0; s < NSTEP; ++s) {
    const int buf = s & 1;
    const bf16_t* AH = &Ash[buf][wr][0];
    const bf16_t* BH = &Bsh[buf][wc >> 1][0];
    const int nrow = (wc & 1) * 64;
    bf16x8 bfr[2][4], af[4];

    // ---- phase 0: kc=0, mt 0..3 (A rows 0..63), load all B kc=0 frags
#pragma unroll
    for (int mt = 0; mt < 4; ++mt) af[mt] = frag(AH, mt * 16 + col, 0);
#pragma unroll
    for (int nt = 0; nt < 4; ++nt) bfr[0][nt] = frag(BH, nrow + nt * 16 + col, 0);
    if (s + 1 < NSTEP) stageA(buf ^ 1, 0, s + 1);
    asm volatile("s_barrier" ::: "memory");
    __builtin_amdgcn_s_setprio(1);
#pragma unroll
    for (int mt = 0; mt < 4; ++mt)
#pragma unroll
      for (int nt = 0; nt < 4; ++nt)
        acc[mt][nt] = __builtin_amdgcn_mfma_f32_16x16x32_bf16(af[mt], bfr[0][nt], acc[mt][nt], 0, 0, 0);
    __builtin_amdgcn_s_setprio(0);
    asm volatile("s_barrier" ::: "memory");

    // ---- phase 1: kc=1, mt 0..3, load all B kc=1 frags
#pragma unroll
    for (int mt = 0; mt < 4; ++mt) af[mt] = frag(AH, mt * 16 + col, 1);
#pragma unroll
    for (int nt = 0; nt < 4; ++nt) bfr[1][nt] = frag(BH, nrow + nt * 16 + col, 1);
    if (s + 1 < NSTEP) stageA(buf ^ 1, 1, s + 1);
    asm volatile("s_barrier" ::: "memory");
    __builtin_amdgcn_s_setprio(1);
#pragma unroll
    for (int mt = 0; mt < 4; ++mt)
#pragma unroll
      for (int nt = 0; nt < 4; ++nt)
        acc[mt][nt] = __builtin_amdgcn_mfma_f32_16x16x32_bf16(af[mt], bfr[1][nt], acc[mt][nt], 0, 0, 0);
    __builtin_amdgcn_s_setprio(0);
    if (s == NSTEP - 1) { asm volatile("s_waitcnt vmcnt(0)" ::: "memory"); }
    else                { asm volatile("s_waitcnt vmcnt(8)" ::: "memory"); }
    asm volatile("s_barrier" ::: "memory");

    // ---- phase 2: kc=0, mt 4..7 (A rows 64..127), reuse bfr[0]
#pragma unroll
    for (int mt = 0; mt < 4; ++mt) af[mt] = frag(AH, (mt + 4) * 16 + col, 0);
    if (s + 2 < NSTEP) stageB(buf, 0, s + 2);
    asm volatile("s_barrier" ::: "memory");
    __builtin_amdgcn_s_setprio(1);
#pragma unroll
    for (int mt = 0; mt < 4; ++mt)
#pragma unroll
      for (int nt = 0; nt < 4; ++nt)
        acc[mt + 4][nt] = __builtin_amdgcn_mfma_f32_16x16x32_bf16(af[mt], bfr[0][nt], acc[mt + 4][nt], 0, 0, 0);
    __builtin_amdgcn_s_setprio(0);
    asm volatile("s_barrier" ::: "memory");

    // ---- phase 3: kc=1, mt 4..7, reuse bfr[1]
#pragma unroll
    for (int mt = 0; mt < 4; ++mt) af[mt] = frag(AH, (mt + 4) * 16 + col, 1);
    if (s + 2 < NSTEP) stageB(buf, 1, s + 2);
    asm volatile("s_barrier" ::: "memory");
    __builtin_amdgcn_s_setprio(1);
#pragma unroll
    for (int mt = 0; mt < 4; ++mt)
#pragma unroll
      for (int nt = 0; nt < 4; ++nt)
        acc[mt + 4][nt] = __builtin_amdgcn_mfma_f32_16x16x32_bf16(af[mt], bfr[1][nt], acc[mt + 4][nt], 0, 0, 0);
    __builtin_amdgcn_s_setprio(0);
    if (s == NSTEP - 2)      { asm volatile("s_waitcnt vmcnt(2)" ::: "memory"); }
    else if (s < NSTEP - 2)  { asm volatile("s_waitcnt vmcnt(6)" ::: "memory"); }
    asm volatile("s_barrier" ::: "memory");
  }

  // epilogue
#pragma unroll
  for (int mt = 0; mt < 8; ++mt)
#pragma unroll
    for (int i = 0; i < 4; ++i) {
      const int row = m0 + wr * 128 + mt * 16 + quad * 4 + i;
#pragma unroll
      for (int nt = 0; nt < 4; ++nt)
        Cout[(size_t)row * N + n0 + wc * 64 + nt * 16 + col] = (OutT)acc[mt][nt][i];
    }
}

// ---------------- fused RoPE (Q and K) + head-major repack ----
__global__ void k_rope2(const bf16_t* __restrict__ in, const float* __restrict__ cs,
                        const float* __restrict__ sn, bf16_t* __restrict__ outQ,
                        bf16_t* __restrict__ outK) {
  const int idx = blockIdx.x * 256 + threadIdx.x;
  const int d = idx & 63;
  const int hh = (idx >> 6) % 20;
  const int bt = idx / (64 * 20);
  const int t = bt & (Tc - 1);
  const int b = bt >> 11;
  const bool isQ = hh < 16;
  const int h = isQ ? hh : hh - 16;
  const int colb = isQ ? h * HDc : 2048 + h * HDc;
  const size_t bi = (size_t)(b * Tc + t) * Nqkv + colb;
  const float x0 = (float)in[bi + d];
  const float x1 = (float)in[bi + d + 64];
  const float c0 = cs[t * HDc + d], c1 = cs[t * HDc + d + 64];
  const float s0 = sn[t * HDc + d], s1 = sn[t * HDc + d + 64];
  bf16_t* op = isQ ? outQ + ((size_t)(b * Hc + h) * Tc + t) * HDc
                   : outK + ((size_t)(b * KVc + h) * Tc + t) * HDc;
  op[d]      = (bf16_t)(x0 * c0 - x1 * s0);
  op[d + 64] = (bf16_t)(x1 * c1 + x0 * s1);
}

// ---------------- V repack: fused rows -> [B,KV,HD,T] --------
__global__ void k_vtrans(const bf16_t* __restrict__ v, bf16_t* __restrict__ vt,
                         int in_stride, int col_off) {
  __shared__ alignas(16) bf16_t tile[64][136];
  const int t0 = blockIdx.x * 64;
  const int kv = blockIdx.y, b = blockIdx.z;
  const int tid = threadIdx.x;
#pragma unroll
  for (int i = 0; i < 4; ++i) {
    int idx = tid + i * 256;
    int r = idx >> 4;
    int ch = idx & 15;
    const bf16_t* gp = v + (size_t)(b * Tc + t0 + r) * in_stride + col_off + kv * HDc + ch * 8;
    *(uint4*)&tile[r][ch * 8] = *(const uint4*)gp;
  }
  __syncthreads();
#pragma unroll
  for (int i = 0; i < 4; ++i) {
    int idx = tid + i * 256;
    int d = idx >> 3;
    int tc = idx & 7;
    alignas(16) bf16_t o[8];
#pragma unroll
    for (int j = 0; j < 8; ++j) o[j] = tile[tc * 8 + j][d];
    bf16_t* gp = vt + ((size_t)(b * KVc + kv) * HDc + d) * Tc + t0 + tc * 8;
    *(uint4*)gp = *(uint4*)o;
  }
}

// ---------------- Flash attention v7: register-resident P ----
__global__ __launch_bounds__(256, 2) void k_attn(
    const bf16_t* __restrict__ Qp, const bf16_t* __restrict__ Kp,
    const bf16_t* __restrict__ Vt, bf16_t* __restrict__ Oout) {
  constexpr float sc2 = 0.08838834764831845f * 1.4426950408889634f; // scale*log2(e)
  __shared__ alignas(16) bf16_t Ksh[2][64 * 128];   // 16 slots, swizzled ^(r&7)
  __shared__ alignas(16) bf16_t Vsh[2][128 * 64];   // 8 slots, swizzled ^(d&7)

  const int i2 = blockIdx.x, h = blockIdx.y, b = blockIdx.z;
  const int kvh = h >> 2;  // REP = 4
  const int tid = threadIdx.x, wave = tid >> 6, lane = tid & 63;
  const int col = lane & 15, quad = lane >> 4;

  const bf16_t* Kb = Kp + (size_t)(b * KVc + kvh) * Tc * HDc;
  const bf16_t* Vb = Vt + (size_t)(b * KVc + kvh) * HDc * Tc;
  const bf16_t* Qbh = Qp + (size_t)(b * Hc + h) * Tc * HDc;

  const int st_kr = lane >> 4, st_kc8 = lane & 15;
  const int st_vr = lane >> 3, st_vc8 = lane & 7;

  const int qb0 = 31 - i2, qb1 = i2;
  const int n0it = qb0 + 1;            // iters in pass 0
  const int ntot = qb0 + qb1 + 2;      // 33 total

  int q0 = qb0 * 64 + wave * 16;
  const int qr = wave * 16 + col;      // this lane's q-row within the 64-q block

  bf16x8 qf[4];
  {
    const bf16_t* qbase = Qbh + (size_t)(q0 + col) * HDc;
#pragma unroll
    for (int kc = 0; kc < 4; ++kc) {
      bf16x8 raw = *(const bf16x8*)(qbase + kc * 32 + quad * 8);
#pragma unroll
      for (int e = 0; e < 8; ++e) qf[kc][e] = (bf16_t)((float)raw[e] * sc2);
    }
  }

  f32x4 o_acc[8];
#pragma unroll
  for (int nb = 0; nb < 8; ++nb) o_acc[nb] = f32x4{0.f, 0.f, 0.f, 0.f};
  float l_i = 0.f;

#pragma unroll
  for (int i = 0; i < 4; ++i) {
    const int rb = wave * 16 + i * 4;
    const int r = rb + st_kr;
    const int kc8 = st_kc8 ^ (r & 7);
    gload_lds16(Kb + (size_t)r * HDc + kc8 * 8, &Ksh[0][rb * 128]);
    const int db = wave * 32 + i * 8;
    const int d = db + st_vr;
    const int tc8 = st_vc8 ^ (d & 7);
    gload_lds16(Vb + (size_t)d * Tc + tc8 * 8, &Vsh[0][db * 64]);
  }

#pragma unroll 1
  for (int j = 0; j < ntot; ++j) {
    const int cur = j & 1;
    const bool diag = (j == qb0) || (j == ntot - 1);
    asm volatile("s_barrier" ::: "memory");
    {
      const int jn = (j + 1 < ntot) ? (j + 1) : (ntot - 1);
      const int tn = (jn < n0it) ? jn : (jn - n0it);
      const int kbn = tn * 64;
#pragma unroll
      for (int i = 0; i < 4; ++i) {
        const int rb = wave * 16 + i * 4;
        const int r = rb + st_kr;
        const int kc8 = st_kc8 ^ (r & 7);
        gload_lds16(Kb + (size_t)(kbn + r) * HDc + kc8 * 8, &Ksh[cur ^ 1][rb * 128]);
        const int db = wave * 32 + i * 8;
        const int d = db + st_vr;
        const int tc8 = st_vc8 ^ (d & 7);
        gload_lds16(Vb + (size_t)d * Tc + kbn + tc8 * 8, &Vsh[cur ^ 1][db * 64]);
      }
    }
    asm volatile("s_waitcnt vmcnt(8)" ::: "memory");
    asm volatile("s_barrier" ::: "memory");

    const bf16_t* Kc = &Ksh[cur][0];
    const bf16_t* Vc = &Vsh[cur][0];

    // S^T tile via swapped operands: st[tb] holds S[q=col][kv=16tb+4quad+i]
    f32x4 st[4];
#pragma unroll
    for (int tb = 0; tb < 4; ++tb) st[tb] = f32x4{0.f, 0.f, 0.f, 0.f};
#pragma unroll
    for (int kc = 0; kc < 4; ++kc)
#pragma unroll
      for (int tb = 0; tb < 4; ++tb) {
        const int r = tb * 16 + col;
        const int slot = (kc * 4 + quad) ^ (r & 7);
        bf16x8 kf = *(const bf16x8*)(Kc + r * 128 + slot * 8);
        st[tb] = __builtin_amdgcn_mfma_f32_16x16x32_bf16(kf, qf[kc], st[tb], 0, 0, 0);
      }

    unsigned int pwrd[4][2];
#pragma unroll
    for (int tb = 0; tb < 4; ++tb) {
      const int kvb = tb * 16 + quad * 4;
      float e0 = exp2f(st[tb][0]), e1 = exp2f(st[tb][1]);
      float e2 = exp2f(st[tb][2]), e3 = exp2f(st[tb][3]);
      if (diag) {
        e0 = (kvb + 0 > qr) ? 0.f : e0;
        e1 = (kvb + 1 > qr) ? 0.f : e1;
        e2 = (kvb + 2 > qr) ? 0.f : e2;
        e3 = (kvb + 3 > qr) ? 0.f : e3;
      }
      l_i += (e0 + e1) + (e2 + e3);
      pwrd[tb][0] = cvt_pk_bf16(e0, e1);
      pwrd[tb][1] = cvt_pk_bf16(e2, e3);
    }

#pragma unroll
    for (int kc = 0; kc < 2; ++kc) {
      unsigned int a0 = pwrd[2 * kc][0], b0 = pwrd[2 * kc + 1][0];
      unsigned int a1 = pwrd[2 * kc][1], b1 = pwrd[2 * kc + 1][1];
      perm32swap(a0, b0);
      perm32swap(a1, b1);
      perm16swap(a0, b0);
      perm16swap(a1, b1);
      union { unsigned int w[4]; bf16x8 v; } u;
      u.w[0] = a0; u.w[1] = a1; u.w[2] = b0; u.w[3] = b1;
      const bf16x8 pf = u.v;
#pragma unroll
      for (int nb = 0; nb < 8; ++nb) {
        const int d = nb * 16 + col;
        const int vslot = (kc * 4 + quad) ^ (d & 7);
        bf16x8 vf = *(const bf16x8*)(Vc + d * 64 + vslot * 8);
        o_acc[nb] = __builtin_amdgcn_mfma_f32_16x16x32_bf16(pf, vf, o_acc[nb], 0, 0, 0);
      }
    }

    if (j == qb0) {
      float rs = l_i;
      rs += __shfl_xor(rs, 16);
      rs += __shfl_xor(rs, 32);
      const float inv = 1.0f / rs;
#pragma unroll
      for (int i = 0; i < 4; ++i) {
        const float iq = __shfl(inv, quad * 4 + i);
        const int qrow = q0 + quad * 4 + i;
        bf16_t* op = Oout + ((size_t)(b * Tc) + qrow) * (Hc * HDc) + h * HDc;
#pragma unroll
        for (int nb = 0; nb < 8; ++nb) op[nb * 16 + col] = (bf16_t)(o_acc[nb][i] * iq);
      }
      l_i = 0.f;
#pragma unroll
      for (int nb = 0; nb < 8; ++nb) o_acc[nb] = f32x4{0.f, 0.f, 0.f, 0.f};
      q0 = qb1 * 64 + wave * 16;
      const bf16_t* qbase = Qbh + (size_t)(q0 + col) * HDc;
#pragma unroll
      for (int kc = 0; kc < 4; ++kc) {
        bf16x8 raw = *(const bf16x8*)(qbase + kc * 32 + quad * 8);
#pragma unroll
        for (int e = 0; e < 8; ++e) qf[kc][e] = (bf16_t)((float)raw[e] * sc2);
      }
    }
  }

  {
    float rs = l_i;
    rs += __shfl_xor(rs, 16);
    rs += __shfl_xor(rs, 32);
    const float inv = 1.0f / rs;
#pragma unroll
    for (int i = 0; i < 4; ++i) {
      const float iq = __shfl(inv, quad * 4 + i);
      const int qrow = q0 + quad * 4 + i;
      bf16_t* op = Oout + ((size_t)(b * Tc) + qrow) * (Hc * HDc) + h * HDc;
#pragma unroll
      for (int nb = 0; nb < 8; ++nb) op[nb * 16 + col] = (bf16_t)(o_acc[nb][i] * iq);
    }
  }
}

// ---------------- launch ----------------
extern "C" void kernel_launch(void* const* d_in, const int* in_sizes, int n_in,
                              void* d_out, int out_size, void* d_ws, size_t ws_size,
                              hipStream_t stream) {
  (void)in_sizes; (void)n_in; (void)out_size; (void)ws_size;
  const float* x    = (const float*)d_in[0];
  const float* cosT = (const float*)d_in[1];
  const float* sinT = (const float*)d_in[2];
  const float* Wq   = (const float*)d_in[3];
  const float* Wk   = (const float*)d_in[4];
  const float* Wv   = (const float*)d_in[5];
  const float* Wo   = (const float*)d_in[6];
  float* out = (float*)d_out;

  char* ws = (char*)d_ws;
  size_t off = 0;
  auto take = [&](size_t bytes) { char* p = ws + off; off += (bytes + 255) & ~(size_t)255; return p; };

  bf16_t* xb    = (bf16_t*)take((size_t)Mc * Cdim * 2);      // reused as Qp after proj
  bf16_t* Wqkvt = (bf16_t*)take((size_t)Nqkv * Cdim * 2);    // [3072][2048]
  bf16_t* Wot   = (bf16_t*)take((size_t)Cdim * (Hc * HDc) * 2);
  bf16_t* qkv   = (bf16_t*)take((size_t)Mc * Nqkv * 2);      // reused as attn out
  bf16_t* Kp    = (bf16_t*)take((size_t)Mc * (KVc * HDc) * 2);
  bf16_t* Vt    = (bf16_t*)take((size_t)Mc * (KVc * HDc) * 2);
  bf16_t* Wqt = Wqkvt;
  bf16_t* Wkt = Wqkvt + (size_t)2048 * Cdim;
  bf16_t* Wvt = Wqkvt + (size_t)2560 * Cdim;
  bf16_t* Qp   = xb;
  bf16_t* attn = qkv;

  // 1. convert x
  k_cvt_bf16<<<dim3((Mc * Cdim) / 2048), dim3(256), 0, stream>>>(x, xb);
  // 2. transpose-convert weights into fused [3072][2048] (+ Wot)
  k_w_trans<<<dim3(Cdim / 64, 2048 / 64), dim3(256), 0, stream>>>(Wq, Wqt, Cdim, 2048);
  k_w_trans<<<dim3(Cdim / 64, 512 / 64), dim3(256), 0, stream>>>(Wk, Wkt, Cdim, 512);
  k_w_trans<<<dim3(Cdim / 64, 512 / 64), dim3(256), 0, stream>>>(Wv, Wvt, Cdim, 512);
  k_w_trans<<<dim3((Hc * HDc) / 64, Cdim / 64), dim3(256), 0, stream>>>(Wo, Wot, Hc * HDc, Cdim);
  // 3. fused QKV projection: [4096 x 3072] on 256^2 8-phase GEMM (192 blocks)
  k_gemm256<bf16_t><<<dim3(Nqkv / 256, Mc / 256), dim3(512), 0, stream>>>(
      xb, Wqkvt, qkv, Mc, Nqkv, Cdim);
  // 4. fused RoPE Q+K (Q overwrites xb — safe, proj done)
  k_rope2<<<dim3((Bc * Tc * 20 * 64) / 256), dim3(256), 0, stream>>>(
      qkv, cosT, sinT, Qp, Kp);
  // 5. V transpose
  k_vtrans<<<dim3(Tc / 64, KVc, Bc), dim3(256), 0, stream>>>(qkv, Vt, Nqkv, 2560);
  // 6. attention (512 perfectly-balanced paired blocks, 33 iters each)
  k_attn<<<dim3(16, Hc, Bc), dim3(256), 0, stream>>>(Qp, Kp, Vt, attn);
  // 7. output projection, fp32 out, 128 blocks
  k_gemm256<float><<<dim3(Cdim / 256, Mc / 256), dim3(512), 0, stream>>>(
      attn, Wot, out, Mc, Cdim, Hc * HDc);
}

// Round 3
// 287.371 us; speedup vs baseline: 1.1305x; 1.1305x over previous
//
#include <hip/hip_runtime.h>
#include <hip/hip_bf16.h>
#include <math.h>

typedef __bf16 bf16_t;
typedef __bf16 bf16x8 __attribute__((ext_vector_type(8)));
typedef float f32x4 __attribute__((ext_vector_type(4)));

constexpr int Bc = 2, Tc = 2048, Cdim = 2048, Hc = 16, KVc = 4, HDc = 128;
constexpr int Mc = Bc * Tc;      // 4096
constexpr int Nqkv = 3072;       // fused projection width: 2048 Q + 512 K + 512 V

typedef const __attribute__((address_space(1))) void* as1_cptr;
typedef __attribute__((address_space(3))) void* as3_ptr;

__device__ __forceinline__ void gload_lds16(const bf16_t* g, bf16_t* l) {
  __builtin_amdgcn_global_load_lds((as1_cptr)(const void*)g, (as3_ptr)(void*)l, 16, 0, 0);
}

__device__ __forceinline__ unsigned int cvt_pk_bf16(float lo, float hi) {
  unsigned int r;
  asm("v_cvt_pk_bf16_f32 %0, %1, %2" : "=v"(r) : "v"(lo), "v"(hi));
  return r;
}
__device__ __forceinline__ void perm32swap(unsigned int& a, unsigned int& b) {
  asm("v_permlane32_swap_b32 %0, %1" : "+v"(a), "+v"(b));
}
__device__ __forceinline__ void perm16swap(unsigned int& a, unsigned int& b) {
  asm("v_permlane16_swap_b32 %0, %1" : "+v"(a), "+v"(b));
}

// ---------------- prep: x f32->bf16 + 4 weight transpose-converts, 1 launch
// grid ranges: [0,4096) cvt x; then Wq 1024, Wk 256, Wv 256, Wo 1024 tiles.
__global__ void k_prep(const float* __restrict__ x, bf16_t* __restrict__ xb,
                       const float* __restrict__ Wq, const float* __restrict__ Wk,
                       const float* __restrict__ Wv, const float* __restrict__ Wo,
                       bf16_t* __restrict__ Wqt, bf16_t* __restrict__ Wkt,
                       bf16_t* __restrict__ Wvt, bf16_t* __restrict__ Wot) {
  __shared__ alignas(16) bf16_t tile[64][72];
  int bid = blockIdx.x;
  if (bid < 4096) {
    // convert x
    int i = (bid * 256 + threadIdx.x) * 8;
    float4 a = *(const float4*)(x + i);
    float4 b = *(const float4*)(x + i + 4);
    bf16x8 v;
    v[0] = (bf16_t)a.x; v[1] = (bf16_t)a.y; v[2] = (bf16_t)a.z; v[3] = (bf16_t)a.w;
    v[4] = (bf16_t)b.x; v[5] = (bf16_t)b.y; v[6] = (bf16_t)b.z; v[7] = (bf16_t)b.w;
    *(bf16x8*)(xb + i) = v;
    return;
  }
  bid -= 4096;
  const float* W; bf16_t* Wt; int K, N, k0, n0;
  if (bid < 1024)      { W = Wq; Wt = Wqt; K = 2048; N = 2048; k0 = (bid >> 5) * 64; n0 = (bid & 31) * 64; }
  else if (bid < 1280) { bid -= 1024; W = Wk; Wt = Wkt; K = 2048; N = 512; k0 = (bid >> 3) * 64; n0 = (bid & 7) * 64; }
  else if (bid < 1536) { bid -= 1280; W = Wv; Wt = Wvt; K = 2048; N = 512; k0 = (bid >> 3) * 64; n0 = (bid & 7) * 64; }
  else                 { bid -= 1536; W = Wo; Wt = Wot; K = 2048; N = 2048; k0 = (bid >> 5) * 64; n0 = (bid & 31) * 64; }
  const int t = threadIdx.x;
#pragma unroll
  for (int i = 0; i < 4; ++i) {
    int idx = t + i * 256;
    int r = idx >> 4;
    int c4 = (idx & 15) * 4;
    float4 v = *(const float4*)(W + (size_t)(k0 + r) * N + n0 + c4);
    tile[r][c4 + 0] = (bf16_t)v.x; tile[r][c4 + 1] = (bf16_t)v.y;
    tile[r][c4 + 2] = (bf16_t)v.z; tile[r][c4 + 3] = (bf16_t)v.w;
  }
  __syncthreads();
#pragma unroll
  for (int i = 0; i < 4; ++i) {
    int idx = t + i * 256;
    int n = idx >> 4;
    int kc = (idx & 15) * 4;
    alignas(8) bf16_t o[4];
#pragma unroll
    for (int j = 0; j < 4; ++j) o[j] = tile[kc + j][n];
    *(uint2*)(Wt + (size_t)(n0 + n) * K + k0 + kc) = *(uint2*)o;
  }
}

// ---------------- GEMM: C[M,N] = A[M,K] * Bt[N,K]^T (fp32 out, O-proj) ----
__global__ __launch_bounds__(256, 2) void k_gemm_bt(
    const bf16_t* __restrict__ A, const bf16_t* __restrict__ Bt,
    float* __restrict__ Cout, int M, int N, int K) {
  __shared__ alignas(16) bf16_t Ash[128 * 64];
  __shared__ alignas(16) bf16_t Bsh[128 * 64];
  const int tid = threadIdx.x;
  const int wave = tid >> 6, lane = tid & 63;
  const int col = lane & 15, quad = lane >> 4;
  const int m0 = blockIdx.y * 128, n0 = blockIdx.x * 128;
  const int wr = wave >> 1, wc = wave & 1;

  f32x4 acc[4][4];
#pragma unroll
  for (int i = 0; i < 4; ++i)
#pragma unroll
    for (int j = 0; j < 4; ++j) acc[i][j] = f32x4{0.f, 0.f, 0.f, 0.f};

  const int lrow = lane >> 3;
  const int lkc8 = (lane & 7) ^ lrow;

  for (int k0 = 0; k0 < K; k0 += 64) {
    __syncthreads();
#pragma unroll
    for (int i = 0; i < 4; ++i) {
      const int rb = wave * 32 + i * 8;
      gload_lds16(A + (size_t)(m0 + rb + lrow) * K + k0 + lkc8 * 8, Ash + rb * 64);
      gload_lds16(Bt + (size_t)(n0 + rb + lrow) * K + k0 + lkc8 * 8, Bsh + rb * 64);
    }
    __syncthreads();
#pragma unroll
    for (int kc = 0; kc < 2; ++kc) {
      bf16x8 af[4], bfr[4];
#pragma unroll
      for (int mt = 0; mt < 4; ++mt) {
        const int m = wr * 64 + mt * 16 + col;
        const int slot = (kc * 4 + quad) ^ (m & 7);
        af[mt] = *(const bf16x8*)(Ash + m * 64 + slot * 8);
      }
#pragma unroll
      for (int nt = 0; nt < 4; ++nt) {
        const int n = wc * 64 + nt * 16 + col;
        const int slot = (kc * 4 + quad) ^ (n & 7);
        bfr[nt] = *(const bf16x8*)(Bsh + n * 64 + slot * 8);
      }
#pragma unroll
      for (int mt = 0; mt < 4; ++mt)
#pragma unroll
        for (int nt = 0; nt < 4; ++nt)
          acc[mt][nt] = __builtin_amdgcn_mfma_f32_16x16x32_bf16(
              af[mt], bfr[nt], acc[mt][nt], 0, 0, 0);
    }
  }
#pragma unroll
  for (int mt = 0; mt < 4; ++mt)
#pragma unroll
    for (int i = 0; i < 4; ++i) {
      const int row = m0 + wr * 64 + mt * 16 + quad * 4 + i;
#pragma unroll
      for (int nt = 0; nt < 4; ++nt)
        Cout[(size_t)row * N + n0 + wc * 64 + nt * 16 + col] = acc[mt][nt][i];
    }
}

// ---------------- fused QKV GEMM + RoPE + head-repack + V-transpose ------
// Same staging/swizzle/MFMA structure as k_gemm_bt, but waves own 32 rows x
// 128 cols so each rope pair (d, d+64) = (acc[mt][nt], acc[mt][nt+4]) is
// register-local. N-tiles (128) align with heads: bx 0-15 Q, 16-19 K, 20-23 V.
// RoPE applied to fp32 accumulators, single bf16 rounding. V written
// transposed to [B,KV,HD,T]. Eliminates qkv intermediate + 2 kernels.
__global__ __launch_bounds__(256, 2) void k_gemm_qkv(
    const bf16_t* __restrict__ A, const bf16_t* __restrict__ Bt,
    const float* __restrict__ cs, const float* __restrict__ sn,
    bf16_t* __restrict__ Qp, bf16_t* __restrict__ Kp, bf16_t* __restrict__ Vt) {
  constexpr int K = Cdim;
  __shared__ alignas(16) bf16_t Ash[128 * 64];
  __shared__ alignas(16) bf16_t Bsh[128 * 64];
  const int tid = threadIdx.x;
  const int wave = tid >> 6, lane = tid & 63;
  const int col = lane & 15, quad = lane >> 4;
  const int m0 = blockIdx.y * 128, n0 = blockIdx.x * 128;

  f32x4 acc[2][8];
#pragma unroll
  for (int i = 0; i < 2; ++i)
#pragma unroll
    for (int j = 0; j < 8; ++j) acc[i][j] = f32x4{0.f, 0.f, 0.f, 0.f};

  const int lrow = lane >> 3;
  const int lkc8 = (lane & 7) ^ lrow;

  for (int k0 = 0; k0 < K; k0 += 64) {
    __syncthreads();
#pragma unroll
    for (int i = 0; i < 4; ++i) {
      const int rb = wave * 32 + i * 8;
      gload_lds16(A + (size_t)(m0 + rb + lrow) * K + k0 + lkc8 * 8, Ash + rb * 64);
      gload_lds16(Bt + (size_t)(n0 + rb + lrow) * K + k0 + lkc8 * 8, Bsh + rb * 64);
    }
    __syncthreads();
#pragma unroll
    for (int kc = 0; kc < 2; ++kc) {
      bf16x8 af[2], bfr[8];
#pragma unroll
      for (int mt = 0; mt < 2; ++mt) {
        const int m = wave * 32 + mt * 16 + col;
        const int slot = (kc * 4 + quad) ^ (m & 7);
        af[mt] = *(const bf16x8*)(Ash + m * 64 + slot * 8);
      }
#pragma unroll
      for (int nt = 0; nt < 8; ++nt) {
        const int n = nt * 16 + col;
        const int slot = (kc * 4 + quad) ^ (n & 7);
        bfr[nt] = *(const bf16x8*)(Bsh + n * 64 + slot * 8);
      }
#pragma unroll
      for (int mt = 0; mt < 2; ++mt)
#pragma unroll
        for (int nt = 0; nt < 8; ++nt)
          acc[mt][nt] = __builtin_amdgcn_mfma_f32_16x16x32_bf16(
              af[mt], bfr[nt], acc[mt][nt], 0, 0, 0);
    }
  }

  const int bx = n0 >> 7;   // head-tile: 0-15 Q, 16-19 K, 20-23 V
  if (bx < 20) {
    const bool isQ = bx < 16;
#pragma unroll
    for (int mt = 0; mt < 2; ++mt)
#pragma unroll
      for (int i = 0; i < 4; ++i) {
        const int row = m0 + wave * 32 + mt * 16 + quad * 4 + i;
        const int b = row >> 11, t = row & (Tc - 1);
        bf16_t* op = isQ ? Qp + ((size_t)(b * Hc + bx) * Tc + t) * HDc
                         : Kp + ((size_t)(b * KVc + (bx - 16)) * Tc + t) * HDc;
        const float* cr = cs + t * HDc;
        const float* sr = sn + t * HDc;
#pragma unroll
        for (int nt = 0; nt < 4; ++nt) {
          const int d = nt * 16 + col;
          const float c = cr[d], s = sr[d];
          const float x0 = acc[mt][nt][i], x1 = acc[mt][nt + 4][i];
          op[d]      = (bf16_t)(x0 * c - x1 * s);
          op[d + 64] = (bf16_t)(x1 * c + x0 * s);
        }
      }
  } else {
    const int kv = bx - 20;
#pragma unroll
    for (int mt = 0; mt < 2; ++mt) {
      const int row0 = m0 + wave * 32 + mt * 16 + quad * 4;
      const int b = row0 >> 11, t0 = row0 & (Tc - 1);
#pragma unroll
      for (int nt = 0; nt < 8; ++nt) {
        const int d = nt * 16 + col;
        alignas(8) bf16_t o[4];
#pragma unroll
        for (int i = 0; i < 4; ++i) o[i] = (bf16_t)acc[mt][nt][i];
        *(uint2*)(Vt + ((size_t)(b * KVc + kv) * HDc + d) * Tc + t0) = *(uint2*)o;
      }
    }
  }
}

// ---------------- Flash attention v7: register-resident P ----
__global__ __launch_bounds__(256, 2) void k_attn(
    const bf16_t* __restrict__ Qp, const bf16_t* __restrict__ Kp,
    const bf16_t* __restrict__ Vt, bf16_t* __restrict__ Oout) {
  constexpr float sc2 = 0.08838834764831845f * 1.4426950408889634f; // scale*log2(e)
  __shared__ alignas(16) bf16_t Ksh[2][64 * 128];   // 16 slots, swizzled ^(r&7)
  __shared__ alignas(16) bf16_t Vsh[2][128 * 64];   // 8 slots, swizzled ^(d&7)

  const int i2 = blockIdx.x, h = blockIdx.y, b = blockIdx.z;
  const int kvh = h >> 2;  // REP = 4
  const int tid = threadIdx.x, wave = tid >> 6, lane = tid & 63;
  const int col = lane & 15, quad = lane >> 4;

  const bf16_t* Kb = Kp + (size_t)(b * KVc + kvh) * Tc * HDc;
  const bf16_t* Vb = Vt + (size_t)(b * KVc + kvh) * HDc * Tc;
  const bf16_t* Qbh = Qp + (size_t)(b * Hc + h) * Tc * HDc;

  const int st_kr = lane >> 4, st_kc8 = lane & 15;
  const int st_vr = lane >> 3, st_vc8 = lane & 7;

  const int qb0 = 31 - i2, qb1 = i2;
  const int n0it = qb0 + 1;            // iters in pass 0
  const int ntot = qb0 + qb1 + 2;      // 33 total

  int q0 = qb0 * 64 + wave * 16;
  const int qr = wave * 16 + col;      // this lane's q-row within the 64-q block

  bf16x8 qf[4];
  {
    const bf16_t* qbase = Qbh + (size_t)(q0 + col) * HDc;
#pragma unroll
    for (int kc = 0; kc < 4; ++kc) {
      bf16x8 raw = *(const bf16x8*)(qbase + kc * 32 + quad * 8);
#pragma unroll
      for (int e = 0; e < 8; ++e) qf[kc][e] = (bf16_t)((float)raw[e] * sc2);
    }
  }

  f32x4 o_acc[8];
#pragma unroll
  for (int nb = 0; nb < 8; ++nb) o_acc[nb] = f32x4{0.f, 0.f, 0.f, 0.f};
  float l_i = 0.f;

#pragma unroll
  for (int i = 0; i < 4; ++i) {
    const int rb = wave * 16 + i * 4;
    const int r = rb + st_kr;
    const int kc8 = st_kc8 ^ (r & 7);
    gload_lds16(Kb + (size_t)r * HDc + kc8 * 8, &Ksh[0][rb * 128]);
    const int db = wave * 32 + i * 8;
    const int d = db + st_vr;
    const int tc8 = st_vc8 ^ (d & 7);
    gload_lds16(Vb + (size_t)d * Tc + tc8 * 8, &Vsh[0][db * 64]);
  }

#pragma unroll 1
  for (int j = 0; j < ntot; ++j) {
    const int cur = j & 1;
    const bool diag = (j == qb0) || (j == ntot - 1);
    asm volatile("s_barrier" ::: "memory");
    {
      const int jn = (j + 1 < ntot) ? (j + 1) : (ntot - 1);
      const int tn = (jn < n0it) ? jn : (jn - n0it);
      const int kbn = tn * 64;
#pragma unroll
      for (int i = 0; i < 4; ++i) {
        const int rb = wave * 16 + i * 4;
        const int r = rb + st_kr;
        const int kc8 = st_kc8 ^ (r & 7);
        gload_lds16(Kb + (size_t)(kbn + r) * HDc + kc8 * 8, &Ksh[cur ^ 1][rb * 128]);
        const int db = wave * 32 + i * 8;
        const int d = db + st_vr;
        const int tc8 = st_vc8 ^ (d & 7);
        gload_lds16(Vb + (size_t)d * Tc + kbn + tc8 * 8, &Vsh[cur ^ 1][db * 64]);
      }
    }
    asm volatile("s_waitcnt vmcnt(8)" ::: "memory");
    asm volatile("s_barrier" ::: "memory");

    const bf16_t* Kc = &Ksh[cur][0];
    const bf16_t* Vc = &Vsh[cur][0];

    // S^T tile via swapped operands: st[tb] holds S[q=col][kv=16tb+4quad+i]
    f32x4 st[4];
#pragma unroll
    for (int tb = 0; tb < 4; ++tb) st[tb] = f32x4{0.f, 0.f, 0.f, 0.f};
#pragma unroll
    for (int kc = 0; kc < 4; ++kc)
#pragma unroll
      for (int tb = 0; tb < 4; ++tb) {
        const int r = tb * 16 + col;
        const int slot = (kc * 4 + quad) ^ (r & 7);
        bf16x8 kf = *(const bf16x8*)(Kc + r * 128 + slot * 8);
        st[tb] = __builtin_amdgcn_mfma_f32_16x16x32_bf16(kf, qf[kc], st[tb], 0, 0, 0);
      }

    unsigned int pwrd[4][2];
#pragma unroll
    for (int tb = 0; tb < 4; ++tb) {
      const int kvb = tb * 16 + quad * 4;
      float e0 = exp2f(st[tb][0]), e1 = exp2f(st[tb][1]);
      float e2 = exp2f(st[tb][2]), e3 = exp2f(st[tb][3]);
      if (diag) {
        e0 = (kvb + 0 > qr) ? 0.f : e0;
        e1 = (kvb + 1 > qr) ? 0.f : e1;
        e2 = (kvb + 2 > qr) ? 0.f : e2;
        e3 = (kvb + 3 > qr) ? 0.f : e3;
      }
      l_i += (e0 + e1) + (e2 + e3);
      pwrd[tb][0] = cvt_pk_bf16(e0, e1);
      pwrd[tb][1] = cvt_pk_bf16(e2, e3);
    }

#pragma unroll
    for (int kc = 0; kc < 2; ++kc) {
      unsigned int a0 = pwrd[2 * kc][0], b0 = pwrd[2 * kc + 1][0];
      unsigned int a1 = pwrd[2 * kc][1], b1 = pwrd[2 * kc + 1][1];
      perm32swap(a0, b0);
      perm32swap(a1, b1);
      perm16swap(a0, b0);
      perm16swap(a1, b1);
      union { unsigned int w[4]; bf16x8 v; } u;
      u.w[0] = a0; u.w[1] = a1; u.w[2] = b0; u.w[3] = b1;
      const bf16x8 pf = u.v;
#pragma unroll
      for (int nb = 0; nb < 8; ++nb) {
        const int d = nb * 16 + col;
        const int vslot = (kc * 4 + quad) ^ (d & 7);
        bf16x8 vf = *(const bf16x8*)(Vc + d * 64 + vslot * 8);
        o_acc[nb] = __builtin_amdgcn_mfma_f32_16x16x32_bf16(pf, vf, o_acc[nb], 0, 0, 0);
      }
    }

    if (j == qb0) {
      float rs = l_i;
      rs += __shfl_xor(rs, 16);
      rs += __shfl_xor(rs, 32);
      const float inv = 1.0f / rs;
#pragma unroll
      for (int i = 0; i < 4; ++i) {
        const float iq = __shfl(inv, quad * 4 + i);
        const int qrow = q0 + quad * 4 + i;
        bf16_t* op = Oout + ((size_t)(b * Tc) + qrow) * (Hc * HDc) + h * HDc;
#pragma unroll
        for (int nb = 0; nb < 8; ++nb) op[nb * 16 + col] = (bf16_t)(o_acc[nb][i] * iq);
      }
      l_i = 0.f;
#pragma unroll
      for (int nb = 0; nb < 8; ++nb) o_acc[nb] = f32x4{0.f, 0.f, 0.f, 0.f};
      q0 = qb1 * 64 + wave * 16;
      const bf16_t* qbase = Qbh + (size_t)(q0 + col) * HDc;
#pragma unroll
      for (int kc = 0; kc < 4; ++kc) {
        bf16x8 raw = *(const bf16x8*)(qbase + kc * 32 + quad * 8);
#pragma unroll
        for (int e = 0; e < 8; ++e) qf[kc][e] = (bf16_t)((float)raw[e] * sc2);
      }
    }
  }

  {
    float rs = l_i;
    rs += __shfl_xor(rs, 16);
    rs += __shfl_xor(rs, 32);
    const float inv = 1.0f / rs;
#pragma unroll
    for (int i = 0; i < 4; ++i) {
      const float iq = __shfl(inv, quad * 4 + i);
      const int qrow = q0 + quad * 4 + i;
      bf16_t* op = Oout + ((size_t)(b * Tc) + qrow) * (Hc * HDc) + h * HDc;
#pragma unroll
      for (int nb = 0; nb < 8; ++nb) op[nb * 16 + col] = (bf16_t)(o_acc[nb][i] * iq);
    }
  }
}

// ---------------- launch ----------------
extern "C" void kernel_launch(void* const* d_in, const int* in_sizes, int n_in,
                              void* d_out, int out_size, void* d_ws, size_t ws_size,
                              hipStream_t stream) {
  (void)in_sizes; (void)n_in; (void)out_size; (void)ws_size;
  const float* x    = (const float*)d_in[0];
  const float* cosT = (const float*)d_in[1];
  const float* sinT = (const float*)d_in[2];
  const float* Wq   = (const float*)d_in[3];
  const float* Wk   = (const float*)d_in[4];
  const float* Wv   = (const float*)d_in[5];
  const float* Wo   = (const float*)d_in[6];
  float* out = (float*)d_out;

  char* ws = (char*)d_ws;
  size_t off = 0;
  auto take = [&](size_t bytes) { char* p = ws + off; off += (bytes + 255) & ~(size_t)255; return p; };

  bf16_t* xb    = (bf16_t*)take((size_t)Mc * Cdim * 2);      // reused as attn-out
  bf16_t* Wqkvt = (bf16_t*)take((size_t)Nqkv * Cdim * 2);    // [3072][2048]
  bf16_t* Wot   = (bf16_t*)take((size_t)Cdim * (Hc * HDc) * 2);
  bf16_t* Qp    = (bf16_t*)take((size_t)Mc * (Hc * HDc) * 2);
  bf16_t* Kp    = (bf16_t*)take((size_t)Mc * (KVc * HDc) * 2);
  bf16_t* Vt    = (bf16_t*)take((size_t)Mc * (KVc * HDc) * 2);
  bf16_t* Wqt = Wqkvt;
  bf16_t* Wkt = Wqkvt + (size_t)2048 * Cdim;
  bf16_t* Wvt = Wqkvt + (size_t)2560 * Cdim;
  bf16_t* attn = xb;   // xb dead after QKV projection

  // 1. prep: convert x + transpose-convert all weights (one launch)
  k_prep<<<dim3(4096 + 1024 + 256 + 256 + 1024), dim3(256), 0, stream>>>(
      x, xb, Wq, Wk, Wv, Wo, Wqt, Wkt, Wvt, Wot);
  // 2. fused QKV projection + RoPE + repack + V-transpose (768 blocks)
  k_gemm_qkv<<<dim3(Nqkv / 128, Mc / 128), dim3(256), 0, stream>>>(
      xb, Wqkvt, cosT, sinT, Qp, Kp, Vt);
  // 3. attention (512 perfectly-balanced paired blocks, 33 iters each)
  k_attn<<<dim3(16, Hc, Bc), dim3(256), 0, stream>>>(Qp, Kp, Vt, attn);
  // 4. output projection, fp32 out
  k_gemm_bt<<<dim3(Cdim / 128, Mc / 128), dim3(256), 0, stream>>>(
      attn, Wot, out, Mc, Cdim, Hc * HDc);
}